// Round 3
// baseline (1741.774 us; speedup 1.0000x reference)
//
#include <hip/hip_runtime.h>

// Linear attention, folded form:
//   ctx[b,h]  = (k_ln)^T (v_ln)            (phase A, fused proj+LN+outer-product)
//   T[b]      = blockdiag(ctx/n) @ w_out^T (phase B1)
//   Wc[b]     = w_q^T @ T[b]               (phase B2)
//   out[b]    = x[b] @ Wc[b] + b_out       (phase C)

#define BATCH  8
#define NSEQ   4096
#define DIM    768
#define HEADS  12
#define DH     64
#define KOFF   768     // w_map row offset of k block
#define VOFF   1536    // w_map row offset of v block
#define EPS    1e-5f

#define NCH    128     // rows per block (phase A / C)
#define KC     64      // K-chunk
#define LDT    132     // padded leading dim for staged tiles ([KC][LDT])
#define LDN    68      // padded leading dim for normalized k/v ([NCH][LDN])

// ---------------------------------------------------------------------------
// Phase A: per (b, h, n-chunk): k/v projection GEMM -> per-head LayerNorm ->
// partial ctx = k_ln^T v_ln accumulated into global ctx via atomics.
// grid (NSEQ/NCH, HEADS, BATCH), block 256 (16x16 threads, 8x8 microtile)
// ---------------------------------------------------------------------------
__launch_bounds__(256, 2)
__global__ void kv_ctx_kernel(const float* __restrict__ x,
                              const float* __restrict__ w_map,
                              const float* __restrict__ g_k,
                              const float* __restrict__ b_k,
                              const float* __restrict__ g_v,
                              const float* __restrict__ b_v,
                              float* __restrict__ ctx)
{
    __shared__ float smem[17408];          // 69.6 KB, reused across phases
    float* xs = smem;                      // [KC][LDT]  xs[c][r] (transposed)
    float* ws = smem + KC * LDT;           // [KC][LDT]  ws[c][kv] (transposed)

    const int tid = threadIdx.x;
    const int ty  = tid >> 4, tx = tid & 15;
    const int ty8 = ty * 8,  tx8 = tx * 8;
    const int n0  = blockIdx.x * NCH;
    const int h   = blockIdx.y;
    const int bb  = blockIdx.z;

    const float* xbase = x + ((size_t)bb * NSEQ + n0) * DIM;

    float acc[8][8];
    #pragma unroll
    for (int i = 0; i < 8; ++i)
        #pragma unroll
        for (int j = 0; j < 8; ++j) acc[i][j] = 0.f;

    for (int c0 = 0; c0 < DIM; c0 += KC) {
        // stage x rows (128 x 64) and w_k/w_v rows (64+64 x 64), transposed
        #pragma unroll
        for (int t = 0; t < 8; ++t) {
            int f  = tid + t * 256;        // float4 id, 2048 total
            int r  = f >> 4;               // 0..127
            int c4 = (f & 15) << 2;        // 0..60
            float4 v = *(const float4*)(xbase + (size_t)r * DIM + c0 + c4);
            xs[(c4 + 0) * LDT + r] = v.x;
            xs[(c4 + 1) * LDT + r] = v.y;
            xs[(c4 + 2) * LDT + r] = v.z;
            xs[(c4 + 3) * LDT + r] = v.w;
            int wrow = (r < DH) ? (KOFF + h * DH + r) : (VOFF + h * DH + (r - DH));
            float4 w = *(const float4*)(w_map + (size_t)wrow * DIM + c0 + c4);
            ws[(c4 + 0) * LDT + r] = w.x;
            ws[(c4 + 1) * LDT + r] = w.y;
            ws[(c4 + 2) * LDT + r] = w.z;
            ws[(c4 + 3) * LDT + r] = w.w;
        }
        __syncthreads();
        #pragma unroll 2
        for (int c = 0; c < KC; ++c) {
            float4 a0 = *(const float4*)(xs + c * LDT + ty8);
            float4 a1 = *(const float4*)(xs + c * LDT + ty8 + 4);
            float4 b0 = *(const float4*)(ws + c * LDT + tx8);
            float4 b1 = *(const float4*)(ws + c * LDT + tx8 + 4);
            float a_[8] = {a0.x, a0.y, a0.z, a0.w, a1.x, a1.y, a1.z, a1.w};
            float b_[8] = {b0.x, b0.y, b0.z, b0.w, b1.x, b1.y, b1.z, b1.w};
            #pragma unroll
            for (int i = 0; i < 8; ++i)
                #pragma unroll
                for (int j = 0; j < 8; ++j)
                    acc[i][j] += a_[i] * b_[j];
        }
        __syncthreads();
    }

    // ---- per-head LayerNorm over DH=64 (rows = ty8+i; cols 0..63 = k, 64..127 = v)
    const bool  isv  = (tx >= 8);
    const float* gp  = isv ? g_v : g_k;
    const float* bp  = isv ? b_v : b_k;
    const int dbase  = (tx & 7) * 8;       // position inside the head
    float gg[8], be[8];
    #pragma unroll
    for (int j = 0; j < 8; ++j) { gg[j] = gp[dbase + j]; be[j] = bp[dbase + j]; }

    float* kn = smem;                      // [NCH][LDN]
    float* vn = smem + NCH * LDN;          // [NCH][LDN]
    float* nbuf = isv ? vn : kn;

    #pragma unroll
    for (int i = 0; i < 8; ++i) {
        float s = 0.f, ss = 0.f;
        #pragma unroll
        for (int j = 0; j < 8; ++j) { s += acc[i][j]; ss += acc[i][j] * acc[i][j]; }
        // reduce across the 8 lanes holding this row's 64 values (k and v groups
        // are disjoint in the low 3 lane bits)
        s += __shfl_xor(s, 1); ss += __shfl_xor(ss, 1);
        s += __shfl_xor(s, 2); ss += __shfl_xor(ss, 2);
        s += __shfl_xor(s, 4); ss += __shfl_xor(ss, 4);
        float mu  = s * (1.f / DH);
        float var = ss * (1.f / DH) - mu * mu;
        float rs  = rsqrtf(var + EPS);
        float o[8];
        #pragma unroll
        for (int j = 0; j < 8; ++j) o[j] = (acc[i][j] - mu) * rs * gg[j] + be[j];
        float4* dst = (float4*)(nbuf + (size_t)(ty8 + i) * LDN + dbase);
        dst[0] = make_float4(o[0], o[1], o[2], o[3]);
        dst[1] = make_float4(o[4], o[5], o[6], o[7]);
    }
    __syncthreads();

    // ---- ctx partial: 64x64 = k_ln^T v_ln over this block's 128 rows
    const int d0 = (tid >> 4) << 2;        // 0..60
    const int e0 = (tid & 15) << 2;        // 0..60
    float ca[4][4];
    #pragma unroll
    for (int i = 0; i < 4; ++i)
        #pragma unroll
        for (int j = 0; j < 4; ++j) ca[i][j] = 0.f;

    #pragma unroll 8
    for (int r = 0; r < NCH; ++r) {
        float4 kv = *(const float4*)(kn + (size_t)r * LDN + d0);
        float4 vv = *(const float4*)(vn + (size_t)r * LDN + e0);
        float kk[4] = {kv.x, kv.y, kv.z, kv.w};
        float vl[4] = {vv.x, vv.y, vv.z, vv.w};
        #pragma unroll
        for (int i = 0; i < 4; ++i)
            #pragma unroll
            for (int j = 0; j < 4; ++j)
                ca[i][j] += kk[i] * vl[j];
    }
    float* cbase = ctx + (size_t)(bb * HEADS + h) * DH * DH;
    #pragma unroll
    for (int i = 0; i < 4; ++i)
        #pragma unroll
        for (int j = 0; j < 4; ++j)
            atomicAdd(cbase + (size_t)(d0 + i) * DH + (e0 + j), ca[i][j]);
}

// ---------------------------------------------------------------------------
// Phase B1: T[b, h*64+d, j] = sum_e (ctx[b,h,d,e]/n) * w_out[j, h*64+e]
// grid (3, HEADS, BATCH), block 256 (each thread owns one j, all 64 d's)
// ---------------------------------------------------------------------------
__launch_bounds__(256)
__global__ void ctx_wout_kernel(const float* __restrict__ ctx,
                                const float* __restrict__ w_out,
                                float* __restrict__ T)
{
    __shared__ float cs[DH * DH];
    const int tid = threadIdx.x;
    const int jt = blockIdx.x, h = blockIdx.y, bb = blockIdx.z;
    const float scale = 1.f / NSEQ;
    const float* cbase = ctx + (size_t)(bb * HEADS + h) * DH * DH;
    for (int t = tid; t < DH * DH; t += 256) cs[t] = cbase[t] * scale;
    __syncthreads();

    const int j = jt * 256 + tid;
    float w[DH];
    const float* wrow = w_out + (size_t)j * DIM + h * DH;
    #pragma unroll
    for (int e4 = 0; e4 < DH; e4 += 4) {
        float4 v = *(const float4*)(wrow + e4);
        w[e4] = v.x; w[e4 + 1] = v.y; w[e4 + 2] = v.z; w[e4 + 3] = v.w;
    }
    float* trow = T + ((size_t)bb * DIM + h * DH) * DIM + j;
    for (int d = 0; d < DH; ++d) {
        float a = 0.f;
        #pragma unroll
        for (int e = 0; e < DH; ++e) a += cs[d * DH + e] * w[e];
        trow[(size_t)d * DIM] = a;
    }
}

// ---------------------------------------------------------------------------
// Phase B2: Wc[b] = w_q^T @ T[b]   (both operands K-major, 768^3 per batch)
// grid (DIM/128, DIM/128, BATCH), block 256
// ---------------------------------------------------------------------------
__launch_bounds__(256, 2)
__global__ void fold_q_kernel(const float* __restrict__ w_map,
                              const float* __restrict__ T,
                              float* __restrict__ Wc)
{
    __shared__ float smem[2 * KC * LDT];
    float* as_ = smem;                     // [KC][LDT]  as_[c][i]
    float* bs_ = smem + KC * LDT;          // [KC][LDT]  bs_[c][j]

    const int tid = threadIdx.x;
    const int ty  = tid >> 4, tx = tid & 15;
    const int ty8 = ty * 8, tx8 = tx * 8;
    const int i0  = blockIdx.x * 128, j0 = blockIdx.y * 128, bb = blockIdx.z;
    const float* tb = T + (size_t)bb * DIM * DIM;

    float acc[8][8];
    #pragma unroll
    for (int i = 0; i < 8; ++i)
        #pragma unroll
        for (int j = 0; j < 8; ++j) acc[i][j] = 0.f;

    for (int c0 = 0; c0 < DIM; c0 += KC) {
        #pragma unroll
        for (int t = 0; t < 8; ++t) {
            int f  = tid + t * 256;
            int ci = f >> 5;               // 0..63
            int c4 = (f & 31) << 2;        // 0..124
            *(float4*)(as_ + ci * LDT + c4) =
                *(const float4*)(w_map + (size_t)(c0 + ci) * DIM + i0 + c4);
            *(float4*)(bs_ + ci * LDT + c4) =
                *(const float4*)(tb + (size_t)(c0 + ci) * DIM + j0 + c4);
        }
        __syncthreads();
        #pragma unroll 2
        for (int c = 0; c < KC; ++c) {
            float4 a0 = *(const float4*)(as_ + c * LDT + ty8);
            float4 a1 = *(const float4*)(as_ + c * LDT + ty8 + 4);
            float4 b0 = *(const float4*)(bs_ + c * LDT + tx8);
            float4 b1 = *(const float4*)(bs_ + c * LDT + tx8 + 4);
            float a_[8] = {a0.x, a0.y, a0.z, a0.w, a1.x, a1.y, a1.z, a1.w};
            float b_[8] = {b0.x, b0.y, b0.z, b0.w, b1.x, b1.y, b1.z, b1.w};
            #pragma unroll
            for (int i = 0; i < 8; ++i)
                #pragma unroll
                for (int j = 0; j < 8; ++j)
                    acc[i][j] += a_[i] * b_[j];
        }
        __syncthreads();
    }

    float* wcb = Wc + (size_t)bb * DIM * DIM + (size_t)i0 * DIM + j0;
    #pragma unroll
    for (int i = 0; i < 8; ++i) {
        *(float4*)(wcb + (size_t)(ty8 + i) * DIM + tx8) =
            make_float4(acc[i][0], acc[i][1], acc[i][2], acc[i][3]);
        *(float4*)(wcb + (size_t)(ty8 + i) * DIM + tx8 + 4) =
            make_float4(acc[i][4], acc[i][5], acc[i][6], acc[i][7]);
    }
}

// ---------------------------------------------------------------------------
// Phase C: out[b] = x[b] @ Wc[b] + b_out
// grid (NSEQ/NCH, DIM/128, BATCH), block 256
// ---------------------------------------------------------------------------
__launch_bounds__(256, 2)
__global__ void final_gemm_kernel(const float* __restrict__ x,
                                  const float* __restrict__ Wc,
                                  const float* __restrict__ b_out,
                                  float* __restrict__ out)
{
    __shared__ float smem[2 * KC * LDT];
    float* xs  = smem;                     // [KC][LDT]  xs[c][r] (transposed)
    float* bs_ = smem + KC * LDT;          // [KC][LDT]  bs_[c][j]

    const int tid = threadIdx.x;
    const int ty  = tid >> 4, tx = tid & 15;
    const int ty8 = ty * 8, tx8 = tx * 8;
    const int n0  = blockIdx.x * NCH, j0 = blockIdx.y * 128, bb = blockIdx.z;

    const float* xbase = x + ((size_t)bb * NSEQ + n0) * DIM;
    const float* wb    = Wc + (size_t)bb * DIM * DIM;

    float acc[8][8];
    #pragma unroll
    for (int i = 0; i < 8; ++i)
        #pragma unroll
        for (int j = 0; j < 8; ++j) acc[i][j] = 0.f;

    for (int c0 = 0; c0 < DIM; c0 += KC) {
        #pragma unroll
        for (int t = 0; t < 8; ++t) {
            int f  = tid + t * 256;
            { // x tile, transposed store
                int r  = f >> 4;           // 0..127
                int c4 = (f & 15) << 2;    // 0..60
                float4 v = *(const float4*)(xbase + (size_t)r * DIM + c0 + c4);
                xs[(c4 + 0) * LDT + r] = v.x;
                xs[(c4 + 1) * LDT + r] = v.y;
                xs[(c4 + 2) * LDT + r] = v.z;
                xs[(c4 + 3) * LDT + r] = v.w;
            }
            { // Wc tile, straight store (already K-major)
                int ci = f >> 5;           // 0..63
                int c4 = (f & 31) << 2;    // 0..124
                *(float4*)(bs_ + ci * LDT + c4) =
                    *(const float4*)(wb + (size_t)(c0 + ci) * DIM + j0 + c4);
            }
        }
        __syncthreads();
        #pragma unroll 2
        for (int c = 0; c < KC; ++c) {
            float4 a0 = *(const float4*)(xs + c * LDT + ty8);
            float4 a1 = *(const float4*)(xs + c * LDT + ty8 + 4);
            float4 b0 = *(const float4*)(bs_ + c * LDT + tx8);
            float4 b1 = *(const float4*)(bs_ + c * LDT + tx8 + 4);
            float a_[8] = {a0.x, a0.y, a0.z, a0.w, a1.x, a1.y, a1.z, a1.w};
            float b_[8] = {b0.x, b0.y, b0.z, b0.w, b1.x, b1.y, b1.z, b1.w};
            #pragma unroll
            for (int i = 0; i < 8; ++i)
                #pragma unroll
                for (int j = 0; j < 8; ++j)
                    acc[i][j] += a_[i] * b_[j];
        }
        __syncthreads();
    }

    float bias[8];
    #pragma unroll
    for (int j = 0; j < 8; ++j) bias[j] = b_out[j0 + tx8 + j];
    float* obase = out + ((size_t)bb * NSEQ + n0) * DIM + j0;
    #pragma unroll
    for (int i = 0; i < 8; ++i) {
        *(float4*)(obase + (size_t)(ty8 + i) * DIM + tx8) =
            make_float4(acc[i][0] + bias[0], acc[i][1] + bias[1],
                        acc[i][2] + bias[2], acc[i][3] + bias[3]);
        *(float4*)(obase + (size_t)(ty8 + i) * DIM + tx8 + 4) =
            make_float4(acc[i][4] + bias[4], acc[i][5] + bias[5],
                        acc[i][6] + bias[6], acc[i][7] + bias[7]);
    }
}

// ---------------------------------------------------------------------------
extern "C" void kernel_launch(void* const* d_in, const int* in_sizes, int n_in,
                              void* d_out, int out_size, void* d_ws, size_t ws_size,
                              hipStream_t stream)
{
    (void)in_sizes; (void)n_in; (void)out_size; (void)ws_size;
    const float* x     = (const float*)d_in[0];
    const float* w_map = (const float*)d_in[1];
    const float* g_k   = (const float*)d_in[2];
    const float* b_k   = (const float*)d_in[3];
    const float* g_v   = (const float*)d_in[4];
    const float* b_v   = (const float*)d_in[5];
    const float* w_out = (const float*)d_in[6];
    const float* b_out = (const float*)d_in[7];
    float* out = (float*)d_out;

    // workspace layout (floats): ctx [8*12*64*64] | T [8*768*768] | Wc [8*768*768]
    float* ctx = (float*)d_ws;
    float* T   = ctx + (size_t)BATCH * HEADS * DH * DH;
    float* Wc  = T   + (size_t)BATCH * DIM * DIM;

    hipMemsetAsync(ctx, 0, (size_t)BATCH * HEADS * DH * DH * sizeof(float), stream);

    dim3 gA(NSEQ / NCH, HEADS, BATCH);
    kv_ctx_kernel<<<gA, 256, 0, stream>>>(x, w_map, g_k, b_k, g_v, b_v, ctx);

    dim3 gB1(DIM / 256, HEADS, BATCH);
    ctx_wout_kernel<<<gB1, 256, 0, stream>>>(ctx, w_out, T);

    dim3 gB2(DIM / 128, DIM / 128, BATCH);
    fold_q_kernel<<<gB2, 256, 0, stream>>>(w_map, T, Wc);

    dim3 gC(NSEQ / NCH, DIM / 128, BATCH);
    final_gemm_kernel<<<gC, 256, 0, stream>>>(x, Wc, b_out, out);
}

// Round 4
// 696.522 us; speedup vs baseline: 2.5007x; 2.5007x over previous
//
#include <hip/hip_runtime.h>

// Linear attention, folded form, f16 MFMA (fp32 accumulate):
//   ctx[b,h]  = (k_ln)^T (v_ln)            (phase A, fused proj+LN+outer-product)
//   T[b]      = blockdiag(ctx/n) @ w_out^T (phase B1, fp32 vector - tiny)
//   WcT[b]    = (w_q^T @ T[b])^T in f16    (phase B2, MFMA)
//   out[b]    = x[b] @ Wc[b] + b_out       (phase C, MFMA)

typedef _Float16 f16;
typedef __attribute__((ext_vector_type(4))) _Float16 f16x4;
typedef __attribute__((ext_vector_type(8))) _Float16 f16x8;
typedef __attribute__((ext_vector_type(4))) float f32x4;

#define MFMA_F16(a, b, c) __builtin_amdgcn_mfma_f32_16x16x32_f16((a), (b), (c), 0, 0, 0)

#define BATCH  8
#define NSEQ   4096
#define DIM    768
#define HEADS  12
#define DH     64
#define KOFF   768
#define VOFF   1536
#define EPS    1e-5f

// LDS tiles: [128 rows][64 halfs] = 128B rows, XOR-swizzled on 16B chunks by (row&7).
// MFMA 16x16x32 f16 fragment maps (gfx950): A: row=l&15, k=(l>>4)*8+j ;
// B: col=l&15, k=(l>>4)*8+j ; C/D: col=l&15, row=(l>>4)*4+reg.
#define SWZ(row, byte) ((row) * 128 + ((byte) ^ (((row) & 7) << 4)))
#define SWZ256(row, byte) ((row) * 256 + ((byte) ^ (((row) & 7) << 4)))

// ---------------------------------------------------------------------------
// Phase A: proj GEMM (MFMA) -> in-register LayerNorm -> transposed f16 LDS ->
// ctx MFMA -> global atomics.  grid (32, 12, 8), block 256 (4 waves 2x2).
// ---------------------------------------------------------------------------
__launch_bounds__(256, 2)
__global__ void kv_ctx_kernel(const float* __restrict__ x,
                              const float* __restrict__ w_map,
                              const float* __restrict__ g_k,
                              const float* __restrict__ b_k,
                              const float* __restrict__ g_v,
                              const float* __restrict__ b_v,
                              float* __restrict__ ctx)
{
    __shared__ __align__(16) char smem[32768];
    // proj phase: xs = smem [128 n][64 c], ws = smem+16K [128 kvfeat][64 c]
    // ctx  phase: kT = smem [64 d][128 n], vT = smem+16K [64 e][128 n]

    const int tid  = threadIdx.x;
    const int lane = tid & 63;
    const int w    = tid >> 6;      // wave 0..3
    const int wr   = w >> 1;        // n-half (proj phase)
    const int wc   = w & 1;         // 0 = k-quadrant, 1 = v-quadrant
    const int l15  = lane & 15;
    const int hi   = lane >> 4;
    const int n0   = blockIdx.x * 128;
    const int h    = blockIdx.y;
    const int bb   = blockIdx.z;

    const float* xbase = x + ((size_t)bb * NSEQ + n0) * DIM;

    f32x4 acc[4][4];
    #pragma unroll
    for (int m = 0; m < 4; ++m)
        #pragma unroll
        for (int n = 0; n < 4; ++n)
            acc[m][n] = (f32x4)(0.f);

    for (int c0 = 0; c0 < DIM; c0 += 64) {
        __syncthreads();
        // stage x (128x64) and w_k|w_v (128x64), fp32 -> f16, swizzled
        #pragma unroll
        for (int t = 0; t < 8; ++t) {
            int f  = tid + t * 256;            // 0..2047
            int r  = f >> 4;                   // 0..127
            int c4 = (f & 15) << 2;            // 0..60
            float4 v = *(const float4*)(xbase + (size_t)r * DIM + c0 + c4);
            f16x4 hx = { (f16)v.x, (f16)v.y, (f16)v.z, (f16)v.w };
            *(f16x4*)(smem + SWZ(r, c4 * 2)) = hx;
            int wrow = (r < DH) ? (KOFF + h * DH + r) : (VOFF + h * DH + r - DH);
            float4 u = *(const float4*)(w_map + (size_t)wrow * DIM + c0 + c4);
            f16x4 hw = { (f16)u.x, (f16)u.y, (f16)u.z, (f16)u.w };
            *(f16x4*)(smem + 16384 + SWZ(r, c4 * 2)) = hw;
        }
        __syncthreads();
        #pragma unroll
        for (int kk = 0; kk < 2; ++kk) {
            const int kb = (kk * 32 + hi * 8) * 2;   // byte offset of k-group
            f16x8 a[4], b[4];
            #pragma unroll
            for (int m = 0; m < 4; ++m) {
                int row = wr * 64 + m * 16 + l15;
                a[m] = *(const f16x8*)(smem + SWZ(row, kb));
            }
            #pragma unroll
            for (int n = 0; n < 4; ++n) {
                int col = wc * 64 + n * 16 + l15;
                b[n] = *(const f16x8*)(smem + 16384 + SWZ(col, kb));
            }
            #pragma unroll
            for (int m = 0; m < 4; ++m)
                #pragma unroll
                for (int n = 0; n < 4; ++n)
                    acc[m][n] = MFMA_F16(a[m], b[n], acc[m][n]);
        }
    }
    __syncthreads();   // protect LDS before LN overwrite

    // ---- LayerNorm over the 64 feature cols of this wave's quadrant.
    // Row r of quadrant lives across 16 lanes (l15) x 4 n-frags; reduce via shfl.
    const float* gp = wc ? g_v : g_k;
    const float* bp = wc ? b_v : b_k;
    float gg[4], be[4];
    #pragma unroll
    for (int n = 0; n < 4; ++n) { gg[n] = gp[n * 16 + l15]; be[n] = bp[n * 16 + l15]; }

    char* tbuf = smem + wc * 16384;   // wc=0 -> kT, wc=1 -> vT  [64 feat][128 n]

    #pragma unroll
    for (int m = 0; m < 4; ++m) {
        float o[4][4];                 // [reg][nfrag]
        #pragma unroll
        for (int r = 0; r < 4; ++r) {
            float s = 0.f, ss = 0.f;
            #pragma unroll
            for (int n = 0; n < 4; ++n) { float t = acc[m][n][r]; s += t; ss += t * t; }
            s += __shfl_xor(s, 1); ss += __shfl_xor(ss, 1);
            s += __shfl_xor(s, 2); ss += __shfl_xor(ss, 2);
            s += __shfl_xor(s, 4); ss += __shfl_xor(ss, 4);
            s += __shfl_xor(s, 8); ss += __shfl_xor(ss, 8);
            float mu  = s * (1.f / DH);
            float var = ss * (1.f / DH) - mu * mu;
            float rs  = rsqrtf(var + EPS);
            #pragma unroll
            for (int n = 0; n < 4; ++n)
                o[r][n] = (acc[m][n][r] - mu) * rs * gg[n] + be[n];
        }
        const int nrow0 = wr * 64 + m * 16 + hi * 4;   // n-index of reg 0
        #pragma unroll
        for (int n = 0; n < 4; ++n) {
            int col = n * 16 + l15;                    // feature 0..63
            f16x4 hv = { (f16)o[0][n], (f16)o[1][n], (f16)o[2][n], (f16)o[3][n] };
            *(f16x4*)(tbuf + SWZ256(col, nrow0 * 2)) = hv;
        }
    }
    __syncthreads();

    // ---- ctx strip per wave: d in [w*16, w*16+16), e 0..63, K = 128 n-rows
    f32x4 c2[4];
    #pragma unroll
    for (int e = 0; e < 4; ++e) c2[e] = (f32x4)(0.f);
    #pragma unroll
    for (int ks = 0; ks < 4; ++ks) {
        const int kb = (ks * 32 + hi * 8) * 2;
        int drow = w * 16 + l15;
        f16x8 ak = *(const f16x8*)(smem + SWZ256(drow, kb));
        #pragma unroll
        for (int e = 0; e < 4; ++e) {
            int col = e * 16 + l15;
            f16x8 bv = *(const f16x8*)(smem + 16384 + SWZ256(col, kb));
            c2[e] = MFMA_F16(ak, bv, c2[e]);
        }
    }
    float* cbase = ctx + (size_t)(bb * HEADS + h) * DH * DH;
    #pragma unroll
    for (int e = 0; e < 4; ++e)
        #pragma unroll
        for (int r = 0; r < 4; ++r) {
            int d  = w * 16 + hi * 4 + r;
            int ee = e * 16 + l15;
            atomicAdd(cbase + d * DH + ee, c2[e][r]);
        }
}

// ---------------------------------------------------------------------------
// Phase B1: T[b, h*64+d, j] = sum_e (ctx[b,h,d,e]/n) * w_out[j, h*64+e]
// fp32 vector, tiny. grid (3, HEADS, BATCH), block 256.
// ---------------------------------------------------------------------------
__launch_bounds__(256)
__global__ void ctx_wout_kernel(const float* __restrict__ ctx,
                                const float* __restrict__ w_out,
                                float* __restrict__ T)
{
    __shared__ float cs[DH * DH];
    const int tid = threadIdx.x;
    const int jt = blockIdx.x, h = blockIdx.y, bb = blockIdx.z;
    const float scale = 1.f / NSEQ;
    const float* cbase = ctx + (size_t)(bb * HEADS + h) * DH * DH;
    for (int t = tid; t < DH * DH; t += 256) cs[t] = cbase[t] * scale;
    __syncthreads();

    const int j = jt * 256 + tid;
    float wv[DH];
    const float* wrow = w_out + (size_t)j * DIM + h * DH;
    #pragma unroll
    for (int e4 = 0; e4 < DH; e4 += 4) {
        float4 v = *(const float4*)(wrow + e4);
        wv[e4] = v.x; wv[e4 + 1] = v.y; wv[e4 + 2] = v.z; wv[e4 + 3] = v.w;
    }
    float* trow = T + ((size_t)bb * DIM + h * DH) * DIM + j;
    for (int d = 0; d < DH; ++d) {
        float a = 0.f;
        #pragma unroll
        for (int e = 0; e < DH; ++e) a += cs[d * DH + e] * wv[e];
        trow[(size_t)d * DIM] = a;
    }
}

// ---------------------------------------------------------------------------
// Phase B2: WcT[b][j][c] = sum_hd T[b,hd,j] * w_map[hd,c]   (f16 out, MFMA)
// grid (6, 6, 8), block 256. Both operands transposed-staged fp32->f16.
// ---------------------------------------------------------------------------
__launch_bounds__(256, 2)
__global__ void fold_q_kernel(const float* __restrict__ w_map,
                              const float* __restrict__ T,
                              f16* __restrict__ WcT)
{
    __shared__ __align__(16) char smem[32768];
    // ts = smem [128 j][64 hd], qs = smem+16K [128 c][64 hd]

    const int tid  = threadIdx.x;
    const int lane = tid & 63;
    const int w    = tid >> 6;
    const int wr   = w >> 1, wc = w & 1;
    const int l15  = lane & 15, hi = lane >> 4;
    const int j0   = blockIdx.x * 128;
    const int c0g  = blockIdx.y * 128;
    const int bb   = blockIdx.z;
    const float* tb = T + (size_t)bb * DIM * DIM;

    f32x4 acc[4][4];
    #pragma unroll
    for (int m = 0; m < 4; ++m)
        #pragma unroll
        for (int n = 0; n < 4; ++n)
            acc[m][n] = (f32x4)(0.f);

    for (int k0 = 0; k0 < DIM; k0 += 64) {
        __syncthreads();
        #pragma unroll
        for (int t = 0; t < 8; ++t) {
            int f  = tid + t * 256;           // 0..2047
            int hd = f >> 5;                  // 0..63 (K row in chunk)
            int p4 = (f & 31) << 2;           // 0..124
            float4 tv = *(const float4*)(tb + (size_t)(k0 + hd) * DIM + j0 + p4);
            #pragma unroll
            for (int q = 0; q < 4; ++q) {
                int j = p4 + q;
                *(f16*)(smem + SWZ(j, hd * 2)) = (f16)((&tv.x)[q]);
            }
            float4 qv = *(const float4*)(w_map + (size_t)(k0 + hd) * DIM + c0g + p4);
            #pragma unroll
            for (int q = 0; q < 4; ++q) {
                int c = p4 + q;
                *(f16*)(smem + 16384 + SWZ(c, hd * 2)) = (f16)((&qv.x)[q]);
            }
        }
        __syncthreads();
        #pragma unroll
        for (int kk = 0; kk < 2; ++kk) {
            const int kb = (kk * 32 + hi * 8) * 2;
            f16x8 a[4], b[4];
            #pragma unroll
            for (int m = 0; m < 4; ++m) {
                int row = wr * 64 + m * 16 + l15;
                a[m] = *(const f16x8*)(smem + SWZ(row, kb));
            }
            #pragma unroll
            for (int n = 0; n < 4; ++n) {
                int col = wc * 64 + n * 16 + l15;
                b[n] = *(const f16x8*)(smem + 16384 + SWZ(col, kb));
            }
            #pragma unroll
            for (int m = 0; m < 4; ++m)
                #pragma unroll
                for (int n = 0; n < 4; ++n)
                    acc[m][n] = MFMA_F16(a[m], b[n], acc[m][n]);
        }
    }

    f16* ob = WcT + (size_t)bb * DIM * DIM;
    #pragma unroll
    for (int m = 0; m < 4; ++m)
        #pragma unroll
        for (int n = 0; n < 4; ++n)
            #pragma unroll
            for (int r = 0; r < 4; ++r) {
                int j = j0 + wr * 64 + m * 16 + hi * 4 + r;
                int c = c0g + wc * 64 + n * 16 + l15;
                ob[(size_t)j * DIM + c] = (f16)acc[m][n][r];
            }
}

// ---------------------------------------------------------------------------
// Phase C: out[b] = x[b] @ Wc[b] + b_out   (MFMA; WcT already f16)
// grid (32, 6, 8), block 256.
// ---------------------------------------------------------------------------
__launch_bounds__(256, 2)
__global__ void final_gemm_kernel(const float* __restrict__ x,
                                  const f16* __restrict__ WcT,
                                  const float* __restrict__ b_out,
                                  float* __restrict__ out)
{
    __shared__ __align__(16) char smem[32768];
    // xs = smem [128 n][64 c], js = smem+16K [128 j][64 c]

    const int tid  = threadIdx.x;
    const int lane = tid & 63;
    const int w    = tid >> 6;
    const int wr   = w >> 1, wc = w & 1;
    const int l15  = lane & 15, hi = lane >> 4;
    const int n0   = blockIdx.x * 128;
    const int j0   = blockIdx.y * 128;
    const int bb   = blockIdx.z;

    const float* xbase = x + ((size_t)bb * NSEQ + n0) * DIM;
    const f16*   wb    = WcT + (size_t)bb * DIM * DIM;

    f32x4 acc[4][4];
    #pragma unroll
    for (int m = 0; m < 4; ++m)
        #pragma unroll
        for (int n = 0; n < 4; ++n)
            acc[m][n] = (f32x4)(0.f);

    for (int c0 = 0; c0 < DIM; c0 += 64) {
        __syncthreads();
        #pragma unroll
        for (int t = 0; t < 8; ++t) {
            int f  = tid + t * 256;
            int r  = f >> 4;                  // 0..127
            int c4 = (f & 15) << 2;           // 0..60
            float4 v = *(const float4*)(xbase + (size_t)r * DIM + c0 + c4);
            f16x4 hx = { (f16)v.x, (f16)v.y, (f16)v.z, (f16)v.w };
            *(f16x4*)(smem + SWZ(r, c4 * 2)) = hx;
            f16x4 hw = *(const f16x4*)(wb + (size_t)(j0 + r) * DIM + c0 + c4);
            *(f16x4*)(smem + 16384 + SWZ(r, c4 * 2)) = hw;
        }
        __syncthreads();
        #pragma unroll
        for (int kk = 0; kk < 2; ++kk) {
            const int kb = (kk * 32 + hi * 8) * 2;
            f16x8 a[4], b[4];
            #pragma unroll
            for (int m = 0; m < 4; ++m) {
                int row = wr * 64 + m * 16 + l15;
                a[m] = *(const f16x8*)(smem + SWZ(row, kb));
            }
            #pragma unroll
            for (int n = 0; n < 4; ++n) {
                int col = wc * 64 + n * 16 + l15;
                b[n] = *(const f16x8*)(smem + 16384 + SWZ(col, kb));
            }
            #pragma unroll
            for (int m = 0; m < 4; ++m)
                #pragma unroll
                for (int n = 0; n < 4; ++n)
                    acc[m][n] = MFMA_F16(a[m], b[n], acc[m][n]);
        }
    }

    float bias[4];
    #pragma unroll
    for (int n = 0; n < 4; ++n) bias[n] = b_out[j0 + wc * 64 + n * 16 + l15];

    float* ob = out + ((size_t)bb * NSEQ + n0) * DIM;
    #pragma unroll
    for (int m = 0; m < 4; ++m)
        #pragma unroll
        for (int n = 0; n < 4; ++n)
            #pragma unroll
            for (int r = 0; r < 4; ++r) {
                int rn = wr * 64 + m * 16 + hi * 4 + r;
                int cj = j0 + wc * 64 + n * 16 + l15;
                ob[(size_t)rn * DIM + cj] = acc[m][n][r] + bias[n];
            }
}

// ---------------------------------------------------------------------------
extern "C" void kernel_launch(void* const* d_in, const int* in_sizes, int n_in,
                              void* d_out, int out_size, void* d_ws, size_t ws_size,
                              hipStream_t stream)
{
    (void)in_sizes; (void)n_in; (void)out_size; (void)ws_size;
    const float* x     = (const float*)d_in[0];
    const float* w_map = (const float*)d_in[1];
    const float* g_k   = (const float*)d_in[2];
    const float* b_k   = (const float*)d_in[3];
    const float* g_v   = (const float*)d_in[4];
    const float* b_v   = (const float*)d_in[5];
    const float* w_out = (const float*)d_in[6];
    const float* b_out = (const float*)d_in[7];
    float* out = (float*)d_out;

    // workspace: ctx f32 [8*12*64*64] | T f32 [8*768*768] | WcT f16 [8*768*768]
    float* ctx = (float*)d_ws;
    float* T   = ctx + (size_t)BATCH * HEADS * DH * DH;
    f16*   WcT = (f16*)(T + (size_t)BATCH * DIM * DIM);

    hipMemsetAsync(ctx, 0, (size_t)BATCH * HEADS * DH * DH * sizeof(float), stream);

    dim3 gA(NSEQ / 128, HEADS, BATCH);
    kv_ctx_kernel<<<gA, 256, 0, stream>>>(x, w_map, g_k, b_k, g_v, b_v, ctx);

    dim3 gB1(DIM / 256, HEADS, BATCH);
    ctx_wout_kernel<<<gB1, 256, 0, stream>>>(ctx, w_out, T);

    dim3 gB2(DIM / 128, DIM / 128, BATCH);
    fold_q_kernel<<<gB2, 256, 0, stream>>>(w_map, T, WcT);

    dim3 gC(NSEQ / 128, DIM / 128, BATCH);
    final_gemm_kernel<<<gC, 256, 0, stream>>>(x, WcT, b_out, out);
}

// Round 7
// 390.757 us; speedup vs baseline: 4.4574x; 1.7825x over previous
//
#include <hip/hip_runtime.h>

// Linear attention, folded form, all GEMMs f16-MFMA + global_load_lds staging:
//   xh,wh     = f16(x), f16(w_map); whqT = f16(w_q)^T      (phase P)
//   ctx[b,h]  = (k_ln)^T (v_ln)                            (phase A, fused)
//   ThT[b]    = (blockdiag(ctx/n) @ w_out^T)^T in f16      (phase B1)
//   WcT[b]    = (w_q^T @ T[b])^T in f16                    (phase B2)
//   out[b]    = x[b] @ Wc[b] + b_out                       (phase C)

typedef _Float16 f16;
typedef __attribute__((ext_vector_type(4))) _Float16 f16x4;
typedef __attribute__((ext_vector_type(8))) _Float16 f16x8;
typedef __attribute__((ext_vector_type(4))) float f32x4;

#define MFMA_F16(a, b, c) __builtin_amdgcn_mfma_f32_16x16x32_f16((a), (b), (c), 0, 0, 0)

#define BATCH  8
#define NSEQ   4096
#define DIM    768
#define HEADS  12
#define DH     64
#define KOFF   768
#define VOFF   1536
#define EPS    1e-5f

// LDS tile rows are 128B (64 f16). Content is XOR-swizzled on 16B chunks by
// (row&7): LDS[row][b] holds global[row][b ^ ((row&7)<<4)]. global_load_lds
// writes LINEARLY (wave base + lane*16), so the swizzle is applied to the
// per-lane GLOBAL source address (rule #21), and reads use SWZ below.
#define SWZ(row, byte) ((row) * 128 + ((byte) ^ (((row) & 7) << 4)))
#define SWZ256(row, byte) ((row) * 256 + ((byte) ^ (((row) & 7) << 4)))

__device__ __forceinline__ void gl16(const void* g, void* l) {
    __builtin_amdgcn_global_load_lds(
        (const __attribute__((address_space(1))) void*)g,
        (__attribute__((address_space(3))) void*)l, 16, 0, 0);
}

// ---------------------------------------------------------------------------
// Phase P: fp32 -> f16 convert (grid-stride, 8 elems/thread)
// ---------------------------------------------------------------------------
__global__ void convert_kernel(const float* __restrict__ src,
                               f16* __restrict__ dst, size_t n8)
{
    size_t i = (size_t)blockIdx.x * blockDim.x + threadIdx.x;
    size_t stride = (size_t)gridDim.x * blockDim.x;
    for (; i < n8; i += stride) {
        const float4* s = (const float4*)(src + i * 8);
        float4 v0 = s[0], v1 = s[1];
        f16x8 h = { (f16)v0.x, (f16)v0.y, (f16)v0.z, (f16)v0.w,
                    (f16)v1.x, (f16)v1.y, (f16)v1.z, (f16)v1.w };
        *(f16x8*)(dst + i * 8) = h;
    }
}

// Phase P2: whqT[c][hd] = f16(w_map[hd][c]), hd,c in [0,768). grid (12,12).
__global__ void transp_q_kernel(const float* __restrict__ w_map,
                                f16* __restrict__ whqT)
{
    __shared__ f16 tl[64][80];
    const int tid = threadIdx.x;
    const int hd0 = blockIdx.x * 64, c0 = blockIdx.y * 64;
    #pragma unroll
    for (int t = 0; t < 4; ++t) {
        int idx = tid + t * 256;
        int r = idx >> 4, c4 = (idx & 15) << 2;
        float4 v = *(const float4*)(w_map + (size_t)(hd0 + r) * DIM + c0 + c4);
        tl[c4 + 0][r] = (f16)v.x;
        tl[c4 + 1][r] = (f16)v.y;
        tl[c4 + 2][r] = (f16)v.z;
        tl[c4 + 3][r] = (f16)v.w;
    }
    __syncthreads();
    #pragma unroll
    for (int t = 0; t < 2; ++t) {
        int idx = tid + t * 256;
        int c = idx >> 3, p = idx & 7;
        f16x8 hv = *(f16x8*)&tl[c][p * 8];
        *(f16x8*)(whqT + (size_t)(c0 + c) * DIM + hd0 + p * 8) = hv;
    }
}

// ---------------------------------------------------------------------------
// Phase A: proj GEMM (MFMA, gl_lds staging) -> in-register LN -> transposed
// f16 LDS -> ctx MFMA -> atomics.  grid (32, 12, 8), block 256 (4 waves 2x2).
// ---------------------------------------------------------------------------
__launch_bounds__(256, 2)
__global__ void kv_ctx_kernel(const f16* __restrict__ xh,
                              const f16* __restrict__ wh,
                              const float* __restrict__ g_k,
                              const float* __restrict__ b_k,
                              const float* __restrict__ g_v,
                              const float* __restrict__ b_v,
                              float* __restrict__ ctx)
{
    __shared__ __align__(16) char smem[32768];

    const int tid  = threadIdx.x;
    const int lane = tid & 63;
    const int w    = tid >> 6;      // wave 0..3
    const int wr   = w >> 1;        // n-half (proj)
    const int wc   = w & 1;         // 0 = k, 1 = v quadrant
    const int l15  = lane & 15;
    const int hi   = lane >> 4;
    const int lr   = lane >> 3;            // 0..7 = row-in-8
    const int lb   = (lane & 7) << 4;      // 0..112 = byte-in-row
    const int srcB = lb ^ (lr << 4);       // inverse-swizzled source byte
    const int n0   = blockIdx.x * 128;
    const int h    = blockIdx.y;
    const int bb   = blockIdx.z;

    const char* px = (const char*)xh
        + ((size_t)(bb * NSEQ + n0 + w * 32 + lr) * DIM) * 2 + srcB;
    const int kvr  = w * 32 + lr;          // 0..127 within [k|v]
    const int wrow = (kvr < DH) ? (KOFF + h * DH + kvr) : (VOFF + h * DH + kvr - DH);
    const char* pw = (const char*)wh + ((size_t)wrow * DIM) * 2 + srcB;
    char* dxb = smem + w * 4096;
    char* dwb = smem + 16384 + w * 4096;

    f32x4 acc[4][4];
    #pragma unroll
    for (int m = 0; m < 4; ++m)
        #pragma unroll
        for (int n = 0; n < 4; ++n)
            acc[m][n] = (f32x4)(0.f);

    for (int c0 = 0; c0 < DIM; c0 += 64) {
        __syncthreads();
        const int kbyt = c0 * 2;
        #pragma unroll
        for (int i = 0; i < 4; ++i) {
            gl16(px + kbyt + i * 12288, dxb + i * 1024);   // 8 rows x 128B
            gl16(pw + kbyt + i * 12288, dwb + i * 1024);
        }
        __syncthreads();
        #pragma unroll
        for (int kk = 0; kk < 2; ++kk) {
            const int kb = (kk * 32 + hi * 8) * 2;
            f16x8 a[4], b[4];
            #pragma unroll
            for (int m = 0; m < 4; ++m) {
                int row = wr * 64 + m * 16 + l15;
                a[m] = *(const f16x8*)(smem + SWZ(row, kb));
            }
            #pragma unroll
            for (int n = 0; n < 4; ++n) {
                int col = wc * 64 + n * 16 + l15;
                b[n] = *(const f16x8*)(smem + 16384 + SWZ(col, kb));
            }
            #pragma unroll
            for (int m = 0; m < 4; ++m)
                #pragma unroll
                for (int n = 0; n < 4; ++n)
                    acc[m][n] = MFMA_F16(a[m], b[n], acc[m][n]);
        }
    }
    __syncthreads();   // protect LDS before LN overwrite

    // ---- LayerNorm over the 64 feature cols of this wave's quadrant.
    const float* gp = wc ? g_v : g_k;
    const float* bp = wc ? b_v : b_k;
    float gg[4], be[4];
    #pragma unroll
    for (int n = 0; n < 4; ++n) { gg[n] = gp[n * 16 + l15]; be[n] = bp[n * 16 + l15]; }

    char* tbuf = smem + wc * 16384;   // wc=0 -> kT, wc=1 -> vT  [64 feat][128 n]

    #pragma unroll
    for (int m = 0; m < 4; ++m) {
        float o[4][4];                 // [reg][nfrag]
        #pragma unroll
        for (int r = 0; r < 4; ++r) {
            float s = 0.f, ss = 0.f;
            #pragma unroll
            for (int n = 0; n < 4; ++n) { float t = acc[m][n][r]; s += t; ss += t * t; }
            s += __shfl_xor(s, 1); ss += __shfl_xor(ss, 1);
            s += __shfl_xor(s, 2); ss += __shfl_xor(ss, 2);
            s += __shfl_xor(s, 4); ss += __shfl_xor(ss, 4);
            s += __shfl_xor(s, 8); ss += __shfl_xor(ss, 8);
            float mu  = s * (1.f / DH);
            float var = ss * (1.f / DH) - mu * mu;
            float rs  = rsqrtf(var + EPS);
            #pragma unroll
            for (int n = 0; n < 4; ++n)
                o[r][n] = (acc[m][n][r] - mu) * rs * gg[n] + be[n];
        }
        const int nrow0 = wr * 64 + m * 16 + hi * 4;
        #pragma unroll
        for (int n = 0; n < 4; ++n) {
            int col = n * 16 + l15;
            f16x4 hv = { (f16)o[0][n], (f16)o[1][n], (f16)o[2][n], (f16)o[3][n] };
            *(f16x4*)(tbuf + SWZ256(col, nrow0 * 2)) = hv;
        }
    }
    __syncthreads();

    // ---- ctx strip per wave: d in [w*16, w*16+16), e 0..63, K = 128 n-rows
    f32x4 c2[4];
    #pragma unroll
    for (int e = 0; e < 4; ++e) c2[e] = (f32x4)(0.f);
    #pragma unroll
    for (int ks = 0; ks < 4; ++ks) {
        const int kb = (ks * 32 + hi * 8) * 2;
        int drow = w * 16 + l15;
        f16x8 ak = *(const f16x8*)(smem + SWZ256(drow, kb));
        #pragma unroll
        for (int e = 0; e < 4; ++e) {
            int col = e * 16 + l15;
            f16x8 bv = *(const f16x8*)(smem + 16384 + SWZ256(col, kb));
            c2[e] = MFMA_F16(ak, bv, c2[e]);
        }
    }
    float* cbase = ctx + (size_t)(bb * HEADS + h) * DH * DH;
    #pragma unroll
    for (int e = 0; e < 4; ++e)
        #pragma unroll
        for (int r = 0; r < 4; ++r) {
            int d  = w * 16 + hi * 4 + r;
            int ee = e * 16 + l15;
            atomicAdd(cbase + d * DH + ee, c2[e][r]);
        }
}

// ---------------------------------------------------------------------------
// Phase B1: ThT[b, j, h*64+d] = sum_e (ctx[b,h,d,e]/n) * w_out[j, h*64+e]
// grid (3, HEADS, BATCH), block 256.
// ---------------------------------------------------------------------------
__launch_bounds__(256)
__global__ void ctx_wout_kernel(const float* __restrict__ ctx,
                                const float* __restrict__ w_out,
                                f16* __restrict__ ThT)
{
    __shared__ float cs[DH * DH];
    const int tid = threadIdx.x;
    const int jt = blockIdx.x, h = blockIdx.y, bb = blockIdx.z;
    const float scale = 1.f / NSEQ;
    const float* cbase = ctx + (size_t)(bb * HEADS + h) * DH * DH;
    for (int t = tid; t < DH * DH; t += 256) cs[t] = cbase[t] * scale;
    __syncthreads();

    const int j = jt * 256 + tid;
    float wv[DH];
    const float* wrow = w_out + (size_t)j * DIM + h * DH;
    #pragma unroll
    for (int e4 = 0; e4 < DH; e4 += 4) {
        float4 v = *(const float4*)(wrow + e4);
        wv[e4] = v.x; wv[e4 + 1] = v.y; wv[e4 + 2] = v.z; wv[e4 + 3] = v.w;
    }
    f16* trow = ThT + ((size_t)bb * DIM + j) * DIM + h * DH;
    for (int d = 0; d < DH; ++d) {
        float a = 0.f;
        #pragma unroll
        for (int e = 0; e < DH; ++e) a += cs[d * DH + e] * wv[e];
        trow[d] = (f16)a;
    }
}

// ---------------------------------------------------------------------------
// Phase B2: WcT[b][j][c] = sum_hd ThT[b,j,hd] * whqT[c,hd]  (MFMA, gl_lds)
// grid (6, 6, 8), block 256.
// ---------------------------------------------------------------------------
__launch_bounds__(256, 2)
__global__ void fold_q_kernel(const f16* __restrict__ ThT,
                              const f16* __restrict__ whqT,
                              f16* __restrict__ WcT)
{
    __shared__ __align__(16) char smem[32768];

    const int tid  = threadIdx.x;
    const int lane = tid & 63;
    const int w    = tid >> 6;
    const int wr   = w >> 1, wc = w & 1;
    const int l15  = lane & 15, hi = lane >> 4;
    const int lr   = lane >> 3;
    const int lb   = (lane & 7) << 4;
    const int srcB = lb ^ (lr << 4);
    const int j0   = blockIdx.x * 128;
    const int c0g  = blockIdx.y * 128;
    const int bb   = blockIdx.z;

    const char* pa = (const char*)ThT
        + ((size_t)(bb * DIM + j0 + w * 32 + lr) * DIM) * 2 + srcB;
    const char* pb = (const char*)whqT
        + ((size_t)(c0g + w * 32 + lr) * DIM) * 2 + srcB;
    char* dab = smem + w * 4096;
    char* dbb = smem + 16384 + w * 4096;

    f32x4 acc[4][4];
    #pragma unroll
    for (int m = 0; m < 4; ++m)
        #pragma unroll
        for (int n = 0; n < 4; ++n)
            acc[m][n] = (f32x4)(0.f);

    for (int k0 = 0; k0 < DIM; k0 += 64) {
        __syncthreads();
        const int kbyt = k0 * 2;
        #pragma unroll
        for (int i = 0; i < 4; ++i) {
            gl16(pa + kbyt + i * 12288, dab + i * 1024);
            gl16(pb + kbyt + i * 12288, dbb + i * 1024);
        }
        __syncthreads();
        #pragma unroll
        for (int kk = 0; kk < 2; ++kk) {
            const int kb = (kk * 32 + hi * 8) * 2;
            f16x8 a[4], b[4];
            #pragma unroll
            for (int m = 0; m < 4; ++m) {
                int row = wr * 64 + m * 16 + l15;
                a[m] = *(const f16x8*)(smem + SWZ(row, kb));
            }
            #pragma unroll
            for (int n = 0; n < 4; ++n) {
                int col = wc * 64 + n * 16 + l15;
                b[n] = *(const f16x8*)(smem + 16384 + SWZ(col, kb));
            }
            #pragma unroll
            for (int m = 0; m < 4; ++m)
                #pragma unroll
                for (int n = 0; n < 4; ++n)
                    acc[m][n] = MFMA_F16(a[m], b[n], acc[m][n]);
        }
    }

    f16* ob = WcT + (size_t)bb * DIM * DIM;
    #pragma unroll
    for (int m = 0; m < 4; ++m)
        #pragma unroll
        for (int n = 0; n < 4; ++n)
            #pragma unroll
            for (int r = 0; r < 4; ++r) {
                int j = j0 + wr * 64 + m * 16 + hi * 4 + r;
                int c = c0g + wc * 64 + n * 16 + l15;
                ob[(size_t)j * DIM + c] = (f16)acc[m][n][r];
            }
}

// ---------------------------------------------------------------------------
// Phase C: out[b] = x[b] @ Wc[b] + b_out   (MFMA, gl_lds)
// grid (32, 6, 8), block 256.
// ---------------------------------------------------------------------------
__launch_bounds__(256, 2)
__global__ void final_gemm_kernel(const f16* __restrict__ xh,
                                  const f16* __restrict__ WcT,
                                  const float* __restrict__ b_out,
                                  float* __restrict__ out)
{
    __shared__ __align__(16) char smem[32768];

    const int tid  = threadIdx.x;
    const int lane = tid & 63;
    const int w    = tid >> 6;
    const int wr   = w >> 1, wc = w & 1;
    const int l15  = lane & 15, hi = lane >> 4;
    const int lr   = lane >> 3;
    const int lb   = (lane & 7) << 4;
    const int srcB = lb ^ (lr << 4);
    const int n0   = blockIdx.x * 128;
    const int j0   = blockIdx.y * 128;
    const int bb   = blockIdx.z;

    const char* pa = (const char*)xh
        + ((size_t)(bb * NSEQ + n0 + w * 32 + lr) * DIM) * 2 + srcB;
    const char* pb = (const char*)WcT
        + ((size_t)(bb * DIM + j0 + w * 32 + lr) * DIM) * 2 + srcB;
    char* dab = smem + w * 4096;
    char* dbb = smem + 16384 + w * 4096;

    f32x4 acc[4][4];
    #pragma unroll
    for (int m = 0; m < 4; ++m)
        #pragma unroll
        for (int n = 0; n < 4; ++n)
            acc[m][n] = (f32x4)(0.f);

    for (int c0 = 0; c0 < DIM; c0 += 64) {
        __syncthreads();
        const int kbyt = c0 * 2;
        #pragma unroll
        for (int i = 0; i < 4; ++i) {
            gl16(pa + kbyt + i * 12288, dab + i * 1024);
            gl16(pb + kbyt + i * 12288, dbb + i * 1024);
        }
        __syncthreads();
        #pragma unroll
        for (int kk = 0; kk < 2; ++kk) {
            const int kb = (kk * 32 + hi * 8) * 2;
            f16x8 a[4], b[4];
            #pragma unroll
            for (int m = 0; m < 4; ++m) {
                int row = wr * 64 + m * 16 + l15;
                a[m] = *(const f16x8*)(smem + SWZ(row, kb));
            }
            #pragma unroll
            for (int n = 0; n < 4; ++n) {
                int col = wc * 64 + n * 16 + l15;
                b[n] = *(const f16x8*)(smem + 16384 + SWZ(col, kb));
            }
            #pragma unroll
            for (int m = 0; m < 4; ++m)
                #pragma unroll
                for (int n = 0; n < 4; ++n)
                    acc[m][n] = MFMA_F16(a[m], b[n], acc[m][n]);
        }
    }

    float bias[4];
    #pragma unroll
    for (int n = 0; n < 4; ++n) bias[n] = b_out[j0 + wc * 64 + n * 16 + l15];

    float* ob = out + ((size_t)bb * NSEQ + n0) * DIM;
    #pragma unroll
    for (int m = 0; m < 4; ++m)
        #pragma unroll
        for (int n = 0; n < 4; ++n)
            #pragma unroll
            for (int r = 0; r < 4; ++r) {
                int rn = wr * 64 + m * 16 + hi * 4 + r;
                int cj = j0 + wc * 64 + n * 16 + l15;
                ob[(size_t)rn * DIM + cj] = acc[m][n][r] + bias[n];
            }
}

// ---------------------------------------------------------------------------
extern "C" void kernel_launch(void* const* d_in, const int* in_sizes, int n_in,
                              void* d_out, int out_size, void* d_ws, size_t ws_size,
                              hipStream_t stream)
{
    (void)in_sizes; (void)n_in; (void)out_size; (void)ws_size;
    const float* x     = (const float*)d_in[0];
    const float* w_map = (const float*)d_in[1];
    const float* g_k   = (const float*)d_in[2];
    const float* b_k   = (const float*)d_in[3];
    const float* g_v   = (const float*)d_in[4];
    const float* b_v   = (const float*)d_in[5];
    const float* w_out = (const float*)d_in[6];
    const float* b_out = (const float*)d_in[7];
    float* out = (float*)d_out;

    // workspace (bytes):
    //   ctx f32 [8*12*64*64]      1.6 MB
    //   xh  f16 [8*4096*768]     50.3 MB
    //   wh  f16 [2304*768]        3.5 MB
    //   whqT f16 [768*768]        1.2 MB
    //   ThT f16 [8*768*768]       9.4 MB
    //   WcT f16 [8*768*768]       9.4 MB
    char* wsb  = (char*)d_ws;
    float* ctx = (float*)wsb;                       wsb += (size_t)BATCH * HEADS * DH * DH * 4;
    f16* xh    = (f16*)wsb;                         wsb += (size_t)BATCH * NSEQ * DIM * 2;
    f16* wh    = (f16*)wsb;                         wsb += (size_t)3 * DIM * DIM * 2;
    f16* whqT  = (f16*)wsb;                         wsb += (size_t)DIM * DIM * 2;
    f16* ThT   = (f16*)wsb;                         wsb += (size_t)BATCH * DIM * DIM * 2;
    f16* WcT   = (f16*)wsb;

    hipMemsetAsync(ctx, 0, (size_t)BATCH * HEADS * DH * DH * sizeof(float), stream);

    convert_kernel<<<2048, 256, 0, stream>>>(x, xh, (size_t)BATCH * NSEQ * DIM / 8);
    convert_kernel<<<864, 256, 0, stream>>>(w_map, wh, (size_t)3 * DIM * DIM / 8);
    dim3 gT(12, 12);
    transp_q_kernel<<<gT, 256, 0, stream>>>(w_map, whqT);

    dim3 gA(NSEQ / 128, HEADS, BATCH);
    kv_ctx_kernel<<<gA, 256, 0, stream>>>(xh, wh, g_k, b_k, g_v, b_v, ctx);

    dim3 gB1(DIM / 256, HEADS, BATCH);
    ctx_wout_kernel<<<gB1, 256, 0, stream>>>(ctx, w_out, ThT);

    dim3 gB2(DIM / 128, DIM / 128, BATCH);
    fold_q_kernel<<<gB2, 256, 0, stream>>>(ThT, whqT, WcT);

    dim3 gC(NSEQ / 128, DIM / 128, BATCH);
    final_gemm_kernel<<<gC, 256, 0, stream>>>(xh, WcT, b_out, out);
}